// Round 1
// baseline (520.687 us; speedup 1.0000x reference)
//
#include <hip/hip_runtime.h>

// Problem constants (fixed by the reference)
constexpr int N_DST1 = 50000;
constexpr int N_DST2 = 10000;
constexpr int E1     = 2000000;
constexpr int E2     = 400000;
constexpr int IN_F   = 128;
constexpr int H_F    = 256;
constexpr int N_CLS  = 47;

// Workspace layout (bytes)
constexpr size_t RP1_OFF = 0;                 // 50001 ints
constexpr size_t RP2_OFF = 200704;            // 10001 ints
constexpr size_t HN1_OFF = 241664;            // 50000*128 f32 = 25.6 MB
constexpr size_t H_OFF   = 25841664;          // 50000*256 f32 = 51.2 MB
constexpr size_t HN2_OFF = 77041664;          // 10000*256 f32 = 10.24 MB
// total ~87.3 MB

// ---- rowptr via binary search (dst is sorted) ----
__global__ void build_rowptr(const int* __restrict__ dst, int E, int n_plus1,
                             int* __restrict__ rp) {
    int idx = blockIdx.x * blockDim.x + threadIdx.x;
    if (idx >= n_plus1) return;
    int target = idx;
    int lo = 0, hi = E;
    while (lo < hi) {
        int mid = (lo + hi) >> 1;
        if (dst[mid] < target) lo = mid + 1; else hi = mid;
    }
    rp[idx] = lo;
}

// ---- layer-1 neighbor mean: one wave per dst node, 128 feats as float2/lane ----
__global__ void agg1(const float* __restrict__ x, const int* __restrict__ src,
                     const int* __restrict__ rp, float* __restrict__ hn) {
    int d = blockIdx.x;
    int s = rp[d], e = rp[d + 1];
    int t = threadIdx.x;  // 0..63
    const float2* x2 = (const float2*)x;
    float2 acc = make_float2(0.f, 0.f);
    int i = s;
    for (; i + 2 <= e; i += 2) {
        int s0 = src[i], s1 = src[i + 1];
        float2 v0 = x2[s0 * 64 + t];
        float2 v1 = x2[s1 * 64 + t];
        acc.x += v0.x + v1.x;
        acc.y += v0.y + v1.y;
    }
    if (i < e) {
        float2 v = x2[src[i] * 64 + t];
        acc.x += v.x; acc.y += v.y;
    }
    float inv = 1.f / fmaxf((float)(e - s), 1.f);
    ((float2*)hn)[d * 64 + t] = make_float2(acc.x * inv, acc.y * inv);
}

// ---- layer-2 neighbor mean: one wave per dst node, 256 feats as float4/lane ----
__global__ void agg2(const float* __restrict__ h, const int* __restrict__ src,
                     const int* __restrict__ rp, float* __restrict__ hn) {
    int d = blockIdx.x;
    int s = rp[d], e = rp[d + 1];
    int t = threadIdx.x;  // 0..63
    const float4* h4 = (const float4*)h;
    float4 acc = make_float4(0.f, 0.f, 0.f, 0.f);
    int i = s;
    for (; i + 2 <= e; i += 2) {
        int s0 = src[i], s1 = src[i + 1];
        float4 v0 = h4[s0 * 64 + t];
        float4 v1 = h4[s1 * 64 + t];
        acc.x += v0.x + v1.x; acc.y += v0.y + v1.y;
        acc.z += v0.z + v1.z; acc.w += v0.w + v1.w;
    }
    if (i < e) {
        float4 v = h4[src[i] * 64 + t];
        acc.x += v.x; acc.y += v.y; acc.z += v.z; acc.w += v.w;
    }
    float inv = 1.f / fmaxf((float)(e - s), 1.f);
    ((float4*)hn)[d * 64 + t] =
        make_float4(acc.x * inv, acc.y * inv, acc.z * inv, acc.w * inv);
}

// ---- layer 1: h = relu(xd@Ws + hn@Wn + b), 64x64 tile, two K-phases of 128 ----
__global__ __launch_bounds__(256) void gemm1(
    const float* __restrict__ x, const float* __restrict__ hn1,
    const float* __restrict__ Ws, const float* __restrict__ Wn,
    const float* __restrict__ b1, float* __restrict__ h) {
    __shared__ float as[16 * 68];  // [k][m], padded to 68 for bank/align
    __shared__ float bs[16 * 64];  // [k][n]
    int tid = threadIdx.x;
    int tx = tid & 15, ty = tid >> 4;  // tx -> col group, ty -> row group
    int R0 = blockIdx.x * 64;
    int C0 = blockIdx.y * 64;
    float acc[4][4] = {};
    for (int t = 0; t < 16; ++t) {
        const float* Ap = (t < 8) ? x : hn1;
        const float* Bp = (t < 8) ? Ws : Wn;
        int kk = (t & 7) * 16;
        int lk = tid & 15, lm0 = tid >> 4;
#pragma unroll
        for (int p = 0; p < 4; ++p) {
            int m = lm0 + p * 16;
            int row = R0 + m;
            as[lk * 68 + m] = (row < N_DST1) ? Ap[row * IN_F + kk + lk] : 0.f;
        }
        int ln = tid & 63, lk2 = tid >> 6;
#pragma unroll
        for (int p = 0; p < 4; ++p) {
            int k = lk2 + p * 4;
            bs[k * 64 + ln] = Bp[(kk + k) * H_F + C0 + ln];
        }
        __syncthreads();
#pragma unroll
        for (int k = 0; k < 16; ++k) {
            float4 a = *(const float4*)&as[k * 68 + 4 * ty];
            float4 b = *(const float4*)&bs[k * 64 + 4 * tx];
            acc[0][0] += a.x * b.x; acc[0][1] += a.x * b.y; acc[0][2] += a.x * b.z; acc[0][3] += a.x * b.w;
            acc[1][0] += a.y * b.x; acc[1][1] += a.y * b.y; acc[1][2] += a.y * b.z; acc[1][3] += a.y * b.w;
            acc[2][0] += a.z * b.x; acc[2][1] += a.z * b.y; acc[2][2] += a.z * b.z; acc[2][3] += a.z * b.w;
            acc[3][0] += a.w * b.x; acc[3][1] += a.w * b.y; acc[3][2] += a.w * b.z; acc[3][3] += a.w * b.w;
        }
        __syncthreads();
    }
    float4 bias = *(const float4*)&b1[C0 + 4 * tx];
#pragma unroll
    for (int i = 0; i < 4; ++i) {
        int row = R0 + 4 * ty + i;
        if (row < N_DST1) {
            float4 o;
            o.x = fmaxf(acc[i][0] + bias.x, 0.f);
            o.y = fmaxf(acc[i][1] + bias.y, 0.f);
            o.z = fmaxf(acc[i][2] + bias.z, 0.f);
            o.w = fmaxf(acc[i][3] + bias.w, 0.f);
            *(float4*)&h[row * H_F + C0 + 4 * tx] = o;
        }
    }
}

// ---- layer 2: out = hd@Ws2 + hn2@Wn2 + b2 ; 8 rows per 64-thread block ----
__global__ __launch_bounds__(64) void gemm2(
    const float* __restrict__ h, const float* __restrict__ hn2,
    const float* __restrict__ Ws, const float* __restrict__ Wn,
    const float* __restrict__ b2, float* __restrict__ out) {
    __shared__ float hs[8 * 512];  // 8 rows x (256 self | 256 neigh)
    int tid = threadIdx.x;  // 0..63
    int d0 = blockIdx.x * 8;
#pragma unroll
    for (int m = 0; m < 8; ++m) {
        int d = d0 + m;
        ((float4*)&hs[m * 512])[tid]       = ((const float4*)&h[d * H_F])[tid];
        ((float4*)&hs[m * 512 + 256])[tid] = ((const float4*)&hn2[d * H_F])[tid];
    }
    __syncthreads();
    if (tid < N_CLS) {
        int j = tid;
        float acc[8] = {};
        for (int k = 0; k < H_F; ++k) {
            float w = Ws[k * N_CLS + j];
#pragma unroll
            for (int m = 0; m < 8; ++m) acc[m] += hs[m * 512 + k] * w;
        }
        for (int k = 0; k < H_F; ++k) {
            float w = Wn[k * N_CLS + j];
#pragma unroll
            for (int m = 0; m < 8; ++m) acc[m] += hs[m * 512 + 256 + k] * w;
        }
        float bb = b2[j];
#pragma unroll
        for (int m = 0; m < 8; ++m) out[(d0 + m) * N_CLS + j] = acc[m] + bb;
    }
}

extern "C" void kernel_launch(void* const* d_in, const int* in_sizes, int n_in,
                              void* d_out, int out_size, void* d_ws, size_t ws_size,
                              hipStream_t stream) {
    const float* x   = (const float*)d_in[0];
    const float* Ws1 = (const float*)d_in[1];
    const float* Wn1 = (const float*)d_in[2];
    const float* b1  = (const float*)d_in[3];
    const float* Ws2 = (const float*)d_in[4];
    const float* Wn2 = (const float*)d_in[5];
    const float* b2  = (const float*)d_in[6];
    const int* src1  = (const int*)d_in[7];
    const int* dst1  = (const int*)d_in[8];
    const int* src2  = (const int*)d_in[9];
    const int* dst2  = (const int*)d_in[10];
    float* out = (float*)d_out;

    char* ws = (char*)d_ws;
    int*   rp1 = (int*)(ws + RP1_OFF);
    int*   rp2 = (int*)(ws + RP2_OFF);
    float* hn1 = (float*)(ws + HN1_OFF);
    float* h   = (float*)(ws + H_OFF);
    float* hn2 = (float*)(ws + HN2_OFF);

    build_rowptr<<<(N_DST1 + 1 + 255) / 256, 256, 0, stream>>>(dst1, E1, N_DST1 + 1, rp1);
    build_rowptr<<<(N_DST2 + 1 + 255) / 256, 256, 0, stream>>>(dst2, E2, N_DST2 + 1, rp2);
    agg1<<<N_DST1, 64, 0, stream>>>(x, src1, rp1, hn1);
    gemm1<<<dim3((N_DST1 + 63) / 64, H_F / 64), 256, 0, stream>>>(x, hn1, Ws1, Wn1, b1, h);
    agg2<<<N_DST2, 64, 0, stream>>>(h, src2, rp2, hn2);
    gemm2<<<N_DST2 / 8, 64, 0, stream>>>(h, hn2, Ws2, Wn2, b2, out);
}

// Round 2
// 426.230 us; speedup vs baseline: 1.2216x; 1.2216x over previous
//
#include <hip/hip_runtime.h>

constexpr int N_DST1 = 50000;
constexpr int N_DST2 = 10000;
constexpr int E1     = 2000000;
constexpr int E2     = 400000;
constexpr int IN_F   = 128;
constexpr int H_F    = 256;
constexpr int N_CLS  = 47;

// Workspace layout (bytes)
constexpr size_t RP1_OFF  = 0;           // 50001 int
constexpr size_t RP2_OFF  = 204800;      // 10001 int
constexpr size_t BPS_OFF  = 245760;      // Ws1 packed: 32768 ushort = 64 KB
constexpr size_t BPN_OFF  = 311296;      // Wn1 packed: 64 KB
constexpr size_t XB_OFF   = 376832;      // x bf16: 200000*128*2 = 51.2 MB
constexpr size_t HN1_OFF  = 51576832;    // hn1 bf16: 50000*128*2 = 12.8 MB
constexpr size_t HB_OFF   = 64376832;    // h bf16: 50000*256*2 = 25.6 MB
constexpr size_t HN2_OFF  = 89976832;    // hn2 bf16: 10000*256*2 = 5.12 MB
// total ~95.1 MB

using f32x4  = __attribute__((ext_vector_type(4))) float;
using short8 = __attribute__((ext_vector_type(8))) short;

__device__ __forceinline__ ushort f2bf(float f) {
    union { float f; unsigned u; } v; v.f = f;
    unsigned u = v.u;
    unsigned r = (u + 0x7fffu + ((u >> 16) & 1u)) >> 16;
    return (ushort)r;
}
__device__ __forceinline__ float bflo(unsigned p) {  // low bf16 of packed pair
    union { unsigned u; float f; } v; v.u = p << 16; return v.f;
}
__device__ __forceinline__ float bfhi(unsigned p) {  // high bf16
    union { unsigned u; float f; } v; v.u = p & 0xffff0000u; return v.f;
}

// ---- x fp32 -> bf16 (4 elems/thread) ----
__global__ __launch_bounds__(256) void cast_x(const float* __restrict__ x,
                                              ushort* __restrict__ xb) {
    int i = blockIdx.x * 256 + threadIdx.x;  // i indexes groups of 4
    float4 v = ((const float4*)x)[i];
    uint2 o;
    o.x = (unsigned)f2bf(v.x) | ((unsigned)f2bf(v.y) << 16);
    o.y = (unsigned)f2bf(v.z) | ((unsigned)f2bf(v.w) << 16);
    ((uint2*)xb)[i] = o;
}

// ---- pack W [128][256] fp32 into MFMA B-fragment order (bf16) ----
// P[((nb*4+kb)*64+lane)*8 + j] = W[kb*32 + (lane>>4)*8 + j][nb*16 + (lane&15)]
__global__ __launch_bounds__(256) void packB(const float* __restrict__ W,
                                             ushort* __restrict__ P) {
    int idx = blockIdx.x * 256 + threadIdx.x;  // 0..4095
    if (idx >= 4096) return;
    int lane = idx & 63, kb = (idx >> 6) & 3, nb = idx >> 8;
    int n  = nb * 16 + (lane & 15);
    int k0 = kb * 32 + ((lane >> 4) * 8);
    ushort tmp[8];
#pragma unroll
    for (int j = 0; j < 8; ++j) tmp[j] = f2bf(W[(k0 + j) * H_F + n]);
    ((uint4*)P)[idx] = *(uint4*)tmp;
}

// ---- rowptr via binary search (dst sorted) ----
__global__ void build_rowptr(const int* __restrict__ dst, int E, int n_plus1,
                             int* __restrict__ rp) {
    int idx = blockIdx.x * blockDim.x + threadIdx.x;
    if (idx >= n_plus1) return;
    int lo = 0, hi = E;
    while (lo < hi) {
        int mid = (lo + hi) >> 1;
        if (dst[mid] < idx) lo = mid + 1; else hi = mid;
    }
    rp[idx] = lo;
}

// ---- layer-1 mean agg over bf16 x: one wave/dst, 2 bf16 per lane ----
__global__ __launch_bounds__(64) void agg1b(const ushort* __restrict__ xb,
                                            const int* __restrict__ src,
                                            const int* __restrict__ rp,
                                            ushort* __restrict__ hn) {
    int d = blockIdx.x, t = threadIdx.x;
    int s = rp[d], e = rp[d + 1];
    const unsigned* x1 = (const unsigned*)xb;  // row stride 64 uints
    float a0 = 0.f, a1 = 0.f;
    int i = s;
    for (; i + 4 <= e; i += 4) {
        int s0 = src[i], s1 = src[i + 1], s2 = src[i + 2], s3 = src[i + 3];
        unsigned v0 = x1[s0 * 64 + t], v1 = x1[s1 * 64 + t];
        unsigned v2 = x1[s2 * 64 + t], v3 = x1[s3 * 64 + t];
        a0 += (bflo(v0) + bflo(v1)) + (bflo(v2) + bflo(v3));
        a1 += (bfhi(v0) + bfhi(v1)) + (bfhi(v2) + bfhi(v3));
    }
    for (; i < e; ++i) {
        unsigned v = x1[src[i] * 64 + t];
        a0 += bflo(v); a1 += bfhi(v);
    }
    float inv = 1.f / fmaxf((float)(e - s), 1.f);
    ((unsigned*)hn)[d * 64 + t] =
        (unsigned)f2bf(a0 * inv) | ((unsigned)f2bf(a1 * inv) << 16);
}

// ---- layer 1 GEMM via bf16 MFMA: one wave = 16 rows x all 256 cols ----
__global__ __launch_bounds__(256) void gemm1_mfma(
    const ushort* __restrict__ xb, const ushort* __restrict__ hn1,
    const ushort* __restrict__ BpS, const ushort* __restrict__ BpN,
    const float* __restrict__ b1, ushort* __restrict__ h) {
    int wave = threadIdx.x >> 6, lane = threadIdx.x & 63;
    int m0 = (blockIdx.x * 4 + wave) * 16;
    if (m0 >= N_DST1) return;
    int mrow = m0 + (lane & 15);
    int koff = (lane >> 4) * 8;

    f32x4 acc[16];
#pragma unroll
    for (int nb = 0; nb < 16; ++nb) acc[nb] = (f32x4){0.f, 0.f, 0.f, 0.f};

#pragma unroll
    for (int ph = 0; ph < 2; ++ph) {
        const ushort* A  = (ph == 0) ? (xb + (size_t)mrow * IN_F)
                                     : (hn1 + (size_t)mrow * IN_F);
        const ushort* Bp = (ph == 0) ? BpS : BpN;
#pragma unroll
        for (int kb = 0; kb < 4; ++kb) {
            short8 a = *(const short8*)(A + kb * 32 + koff);
#pragma unroll
            for (int nb = 0; nb < 16; ++nb) {
                short8 b = *(const short8*)(Bp + ((size_t)(nb * 4 + kb) * 64 + lane) * 8);
                acc[nb] = __builtin_amdgcn_mfma_f32_16x16x32_bf16(a, b, acc[nb], 0, 0, 0);
            }
        }
    }
    // epilogue: row=(lane>>4)*4+r, col=nb*16+(lane&15); bias+relu, bf16 store
    int crow0 = m0 + (lane >> 4) * 4;
    int ccol  = lane & 15;
#pragma unroll
    for (int nb = 0; nb < 16; ++nb) {
        float bias = b1[nb * 16 + ccol];
#pragma unroll
        for (int r = 0; r < 4; ++r) {
            float v = fmaxf(acc[nb][r] + bias, 0.f);
            h[(size_t)(crow0 + r) * H_F + nb * 16 + ccol] = f2bf(v);
        }
    }
}

// ---- layer-2 mean agg over bf16 h: one wave/dst, 4 bf16 per lane ----
__global__ __launch_bounds__(64) void agg2b(const ushort* __restrict__ hb,
                                            const int* __restrict__ src,
                                            const int* __restrict__ rp,
                                            ushort* __restrict__ hn) {
    int d = blockIdx.x, t = threadIdx.x;
    int s = rp[d], e = rp[d + 1];
    const uint2* h2 = (const uint2*)hb;  // row stride 64 uint2
    float a0 = 0.f, a1 = 0.f, a2 = 0.f, a3 = 0.f;
    int i = s;
    for (; i + 2 <= e; i += 2) {
        int s0 = src[i], s1 = src[i + 1];
        uint2 v0 = h2[s0 * 64 + t], v1 = h2[s1 * 64 + t];
        a0 += bflo(v0.x) + bflo(v1.x);
        a1 += bfhi(v0.x) + bfhi(v1.x);
        a2 += bflo(v0.y) + bflo(v1.y);
        a3 += bfhi(v0.y) + bfhi(v1.y);
    }
    if (i < e) {
        uint2 v = h2[src[i] * 64 + t];
        a0 += bflo(v.x); a1 += bfhi(v.x); a2 += bflo(v.y); a3 += bfhi(v.y);
    }
    float inv = 1.f / fmaxf((float)(e - s), 1.f);
    uint2 o;
    o.x = (unsigned)f2bf(a0 * inv) | ((unsigned)f2bf(a1 * inv) << 16);
    o.y = (unsigned)f2bf(a2 * inv) | ((unsigned)f2bf(a3 * inv) << 16);
    ((uint2*)hn)[d * 64 + t] = o;
}

// ---- layer 2: out = hd@Ws2 + hn2@Wn2 + b2 ; 8 rows per 64-thread block ----
__global__ __launch_bounds__(64) void gemm2k(
    const ushort* __restrict__ hb, const ushort* __restrict__ hn2,
    const float* __restrict__ Ws, const float* __restrict__ Wn,
    const float* __restrict__ b2, float* __restrict__ out) {
    __shared__ float hs[8 * 512];
    int tid = threadIdx.x;
    int d0  = blockIdx.x * 8;
#pragma unroll
    for (int m = 0; m < 8; ++m) {
        uint2 v = ((const uint2*)(hb + (size_t)(d0 + m) * H_F))[tid];
        hs[m * 512 + 4 * tid + 0] = bflo(v.x);
        hs[m * 512 + 4 * tid + 1] = bfhi(v.x);
        hs[m * 512 + 4 * tid + 2] = bflo(v.y);
        hs[m * 512 + 4 * tid + 3] = bfhi(v.y);
        uint2 w = ((const uint2*)(hn2 + (size_t)(d0 + m) * H_F))[tid];
        hs[m * 512 + 256 + 4 * tid + 0] = bflo(w.x);
        hs[m * 512 + 256 + 4 * tid + 1] = bfhi(w.x);
        hs[m * 512 + 256 + 4 * tid + 2] = bflo(w.y);
        hs[m * 512 + 256 + 4 * tid + 3] = bfhi(w.y);
    }
    __syncthreads();
    if (tid < N_CLS) {
        int j = tid;
        float acc[8] = {};
        for (int k = 0; k < H_F; ++k) {
            float w = Ws[k * N_CLS + j];
#pragma unroll
            for (int m = 0; m < 8; ++m) acc[m] += hs[m * 512 + k] * w;
        }
        for (int k = 0; k < H_F; ++k) {
            float w = Wn[k * N_CLS + j];
#pragma unroll
            for (int m = 0; m < 8; ++m) acc[m] += hs[m * 512 + 256 + k] * w;
        }
        float bb = b2[j];
#pragma unroll
        for (int m = 0; m < 8; ++m) out[(d0 + m) * N_CLS + j] = acc[m] + bb;
    }
}

extern "C" void kernel_launch(void* const* d_in, const int* in_sizes, int n_in,
                              void* d_out, int out_size, void* d_ws, size_t ws_size,
                              hipStream_t stream) {
    const float* x   = (const float*)d_in[0];
    const float* Ws1 = (const float*)d_in[1];
    const float* Wn1 = (const float*)d_in[2];
    const float* b1  = (const float*)d_in[3];
    const float* Ws2 = (const float*)d_in[4];
    const float* Wn2 = (const float*)d_in[5];
    const float* b2  = (const float*)d_in[6];
    const int* src1  = (const int*)d_in[7];
    const int* dst1  = (const int*)d_in[8];
    const int* src2  = (const int*)d_in[9];
    const int* dst2  = (const int*)d_in[10];
    float* out = (float*)d_out;

    char* ws = (char*)d_ws;
    int*    rp1 = (int*)(ws + RP1_OFF);
    int*    rp2 = (int*)(ws + RP2_OFF);
    ushort* bps = (ushort*)(ws + BPS_OFF);
    ushort* bpn = (ushort*)(ws + BPN_OFF);
    ushort* xb  = (ushort*)(ws + XB_OFF);
    ushort* hn1 = (ushort*)(ws + HN1_OFF);
    ushort* hb  = (ushort*)(ws + HB_OFF);
    ushort* hn2 = (ushort*)(ws + HN2_OFF);

    cast_x<<<(200000 * IN_F / 4 + 255) / 256, 256, 0, stream>>>(x, xb);
    packB<<<16, 256, 0, stream>>>(Ws1, bps);
    packB<<<16, 256, 0, stream>>>(Wn1, bpn);
    build_rowptr<<<(N_DST1 + 1 + 255) / 256, 256, 0, stream>>>(dst1, E1, N_DST1 + 1, rp1);
    build_rowptr<<<(N_DST2 + 1 + 255) / 256, 256, 0, stream>>>(dst2, E2, N_DST2 + 1, rp2);
    agg1b<<<N_DST1, 64, 0, stream>>>(xb, src1, rp1, hn1);
    gemm1_mfma<<<(N_DST1 / 16 + 3) / 4, 256, 0, stream>>>(xb, hn1, bps, bpn, b1, hb);
    agg2b<<<N_DST2, 64, 0, stream>>>(hb, src2, rp2, hn2);
    gemm2k<<<N_DST2 / 8, 64, 0, stream>>>(hb, hn2, Ws2, Wn2, b2, out);
}

// Round 3
// 352.846 us; speedup vs baseline: 1.4757x; 1.2080x over previous
//
#include <hip/hip_runtime.h>

constexpr int N_DST1 = 50000;
constexpr int N_DST2 = 10000;
constexpr int E1     = 2000000;
constexpr int E2     = 400000;
constexpr int IN_F   = 128;
constexpr int H_F    = 256;
constexpr int N_CLS  = 47;

// Workspace layout (bytes)
constexpr size_t RP1_OFF = 0;          // 50001 int
constexpr size_t RP2_OFF = 204800;     // 10001 int
constexpr size_t BPS_OFF = 245760;     // Ws1 packed bf16 frags: 64 KB
constexpr size_t BPN_OFF = 311296;     // Wn1 packed: 64 KB
constexpr size_t BP2_OFF = 376832;     // [Ws2;Wn2] packed: 48 KB
constexpr size_t XB_OFF  = 430080;     // x bf16: 51.2 MB
constexpr size_t HN1_OFF = 51630080;   // hn1 bf16: 12.8 MB
constexpr size_t HB_OFF  = 64430080;   // h bf16: 25.6 MB
constexpr size_t HN2_OFF = 90030080;   // hn2 bf16: 5.12 MB
// total ~95.2 MB

using f32x4  = __attribute__((ext_vector_type(4))) float;
using short8 = __attribute__((ext_vector_type(8))) short;

__device__ __forceinline__ ushort f2bf(float f) {
    union { float f; unsigned u; } v; v.f = f;
    unsigned u = v.u;
    return (ushort)((u + 0x7fffu + ((u >> 16) & 1u)) >> 16);
}
__device__ __forceinline__ float bflo(unsigned p) {
    union { unsigned u; float f; } v; v.u = p << 16; return v.f;
}
__device__ __forceinline__ float bfhi(unsigned p) {
    union { unsigned u; float f; } v; v.u = p & 0xffff0000u; return v.f;
}

// ---- x fp32 -> bf16 ----
__global__ __launch_bounds__(256) void cast_x(const float* __restrict__ x,
                                              ushort* __restrict__ xb) {
    int i = blockIdx.x * 256 + threadIdx.x;
    float4 v = ((const float4*)x)[i];
    uint2 o;
    o.x = (unsigned)f2bf(v.x) | ((unsigned)f2bf(v.y) << 16);
    o.y = (unsigned)f2bf(v.z) | ((unsigned)f2bf(v.w) << 16);
    ((uint2*)xb)[i] = o;
}

// ---- pack W1 [128][256] fp32 -> MFMA B-frag bf16 ----
// P[((nb*4+kb)*64+lane)*8+j] = W[kb*32+(lane>>4)*8+j][nb*16+(lane&15)]
__global__ __launch_bounds__(256) void packB(const float* __restrict__ W,
                                             ushort* __restrict__ P) {
    int idx = blockIdx.x * 256 + threadIdx.x;  // 0..4095
    if (idx >= 4096) return;
    int lane = idx & 63, kb = (idx >> 6) & 3, nb = idx >> 8;
    int n  = nb * 16 + (lane & 15);
    int k0 = kb * 32 + ((lane >> 4) * 8);
    ushort tmp[8];
#pragma unroll
    for (int j = 0; j < 8; ++j) tmp[j] = f2bf(W[(k0 + j) * H_F + n]);
    ((uint4*)P)[idx] = *(uint4*)tmp;
}

// ---- pack [Ws2;Wn2] [512][47] fp32 -> MFMA B-frag bf16, N padded to 48 ----
// P[((kb*3+nb)*64+lane)*8+j]; kb 0..15 over combined K=512
__global__ __launch_bounds__(256) void packB2(const float* __restrict__ Ws,
                                              const float* __restrict__ Wn,
                                              ushort* __restrict__ P) {
    int idx = blockIdx.x * 256 + threadIdx.x;  // 0..3071
    if (idx >= 3072) return;
    int lane = idx & 63, rem = idx >> 6;
    int nb = rem % 3, kb = rem / 3;
    int col = nb * 16 + (lane & 15);
    int k0  = (kb & 7) * 32 + ((lane >> 4) * 8);
    const float* W = (kb < 8) ? Ws : Wn;
    ushort tmp[8];
#pragma unroll
    for (int j = 0; j < 8; ++j)
        tmp[j] = (col < N_CLS) ? f2bf(W[(k0 + j) * N_CLS + col]) : (ushort)0;
    ((uint4*)P)[((kb * 3 + nb) * 64 + lane)] = *(uint4*)tmp;
}

// ---- rowptr via binary search (dst sorted) ----
__global__ void build_rowptr(const int* __restrict__ dst, int E, int n_plus1,
                             int* __restrict__ rp) {
    int idx = blockIdx.x * blockDim.x + threadIdx.x;
    if (idx >= n_plus1) return;
    int lo = 0, hi = E;
    while (lo < hi) {
        int mid = (lo + hi) >> 1;
        if (dst[mid] < idx) lo = mid + 1; else hi = mid;
    }
    rp[idx] = lo;
}

// ---- layer-1 mean agg: one wave/dst; src indices via shfl broadcast ----
__global__ __launch_bounds__(64) void agg1b(const ushort* __restrict__ xb,
                                            const int* __restrict__ src,
                                            const int* __restrict__ rp,
                                            ushort* __restrict__ hn) {
    int d = blockIdx.x, t = threadIdx.x;
    int s = rp[d], e = rp[d + 1];
    const unsigned* x1 = (const unsigned*)xb;  // row stride 64 uints
    float a0 = 0.f, a1 = 0.f;
    for (int base = s; base < e; base += 64) {
        int rem = e - base;
        int n = rem < 64 ? rem : 64;
        int idx = src[base + (t < rem ? t : 0)];  // one coalesced load / 64 edges
        int j = 0;
        for (; j + 4 <= n; j += 4) {
            int s0 = __shfl(idx, j), s1 = __shfl(idx, j + 1);
            int s2 = __shfl(idx, j + 2), s3 = __shfl(idx, j + 3);
            unsigned v0 = x1[s0 * 64 + t], v1 = x1[s1 * 64 + t];
            unsigned v2 = x1[s2 * 64 + t], v3 = x1[s3 * 64 + t];
            a0 += (bflo(v0) + bflo(v1)) + (bflo(v2) + bflo(v3));
            a1 += (bfhi(v0) + bfhi(v1)) + (bfhi(v2) + bfhi(v3));
        }
        for (; j < n; ++j) {
            int sj = __shfl(idx, j);
            unsigned v = x1[sj * 64 + t];
            a0 += bflo(v); a1 += bfhi(v);
        }
    }
    float inv = 1.f / fmaxf((float)(e - s), 1.f);
    ((unsigned*)hn)[d * 64 + t] =
        (unsigned)f2bf(a0 * inv) | ((unsigned)f2bf(a1 * inv) << 16);
}

// ---- layer-2 mean agg: one wave/dst, uint2/lane; shfl broadcast ----
__global__ __launch_bounds__(64) void agg2b(const ushort* __restrict__ hb,
                                            const int* __restrict__ src,
                                            const int* __restrict__ rp,
                                            ushort* __restrict__ hn) {
    int d = blockIdx.x, t = threadIdx.x;
    int s = rp[d], e = rp[d + 1];
    const uint2* h2 = (const uint2*)hb;  // row stride 64 uint2
    float a0 = 0.f, a1 = 0.f, a2 = 0.f, a3 = 0.f;
    for (int base = s; base < e; base += 64) {
        int rem = e - base;
        int n = rem < 64 ? rem : 64;
        int idx = src[base + (t < rem ? t : 0)];
        int j = 0;
        for (; j + 2 <= n; j += 2) {
            int s0 = __shfl(idx, j), s1 = __shfl(idx, j + 1);
            uint2 v0 = h2[s0 * 64 + t], v1 = h2[s1 * 64 + t];
            a0 += bflo(v0.x) + bflo(v1.x);
            a1 += bfhi(v0.x) + bfhi(v1.x);
            a2 += bflo(v0.y) + bflo(v1.y);
            a3 += bfhi(v0.y) + bfhi(v1.y);
        }
        if (j < n) {
            int sj = __shfl(idx, j);
            uint2 v = h2[sj * 64 + t];
            a0 += bflo(v.x); a1 += bfhi(v.x); a2 += bflo(v.y); a3 += bfhi(v.y);
        }
    }
    float inv = 1.f / fmaxf((float)(e - s), 1.f);
    uint2 o;
    o.x = (unsigned)f2bf(a0 * inv) | ((unsigned)f2bf(a1 * inv) << 16);
    o.y = (unsigned)f2bf(a2 * inv) | ((unsigned)f2bf(a3 * inv) << 16);
    ((uint2*)hn)[d * 64 + t] = o;
}

// ---- layer 1 GEMM (MFMA, B staged in LDS; block = 4 waves x 16 rows) ----
__global__ __launch_bounds__(256) void gemm1_mfma(
    const ushort* __restrict__ xb, const ushort* __restrict__ hn1,
    const ushort* __restrict__ BpS, const ushort* __restrict__ BpN,
    const float* __restrict__ b1, ushort* __restrict__ h) {
    __shared__ ushort bsm[16 * 64 * 8];  // 16 KB: one (ph,kb) stage, all 16 nb
    int tid = threadIdx.x;
    int wave = tid >> 6, lane = tid & 63;
    int m0 = (blockIdx.x * 4 + wave) * 16;
    int mrow = m0 + (lane & 15);
    bool active = (m0 < N_DST1);
    if (mrow >= N_DST1) mrow = 0;  // clamp; stores guarded below
    int koff = (lane >> 4) * 8;

    f32x4 acc[16];
#pragma unroll
    for (int nb = 0; nb < 16; ++nb) acc[nb] = (f32x4){0.f, 0.f, 0.f, 0.f};

    for (int ph = 0; ph < 2; ++ph) {
        const uint4* Pg = (const uint4*)((ph == 0) ? BpS : BpN);
        const ushort* A = (ph == 0) ? (xb + (size_t)mrow * IN_F)
                                    : (hn1 + (size_t)mrow * IN_F);
        for (int kb = 0; kb < 4; ++kb) {
            __syncthreads();
#pragma unroll
            for (int i = 0; i < 4; ++i) {
                int u = tid + 256 * i;          // 0..1023 uint4 units
                int nb = u >> 6, l6 = u & 63;
                ((uint4*)bsm)[u] = Pg[(nb * 4 + kb) * 64 + l6];
            }
            __syncthreads();
            short8 a = *(const short8*)(A + kb * 32 + koff);
#pragma unroll
            for (int nb = 0; nb < 16; ++nb) {
                short8 b = *(const short8*)&bsm[(nb * 64 + lane) * 8];
                acc[nb] = __builtin_amdgcn_mfma_f32_16x16x32_bf16(a, b, acc[nb], 0, 0, 0);
            }
        }
    }
    if (!active) return;
    int crow0 = m0 + (lane >> 4) * 4;
    int ccol  = lane & 15;
#pragma unroll
    for (int nb = 0; nb < 16; ++nb) {
        float bias = b1[nb * 16 + ccol];
#pragma unroll
        for (int r = 0; r < 4; ++r) {
            int row = crow0 + r;
            if (row < N_DST1) {
                float v = fmaxf(acc[nb][r] + bias, 0.f);
                h[(size_t)row * H_F + nb * 16 + ccol] = f2bf(v);
            }
        }
    }
}

// ---- layer 2 GEMM (MFMA, K=512 over [h|hn2], N=47 padded to 48) ----
__global__ __launch_bounds__(256) void gemm2_mfma(
    const ushort* __restrict__ hb, const ushort* __restrict__ hn2,
    const ushort* __restrict__ P2, const float* __restrict__ b2,
    float* __restrict__ out) {
    int tid = threadIdx.x;
    int wave = tid >> 6, lane = tid & 63;
    int m0 = (blockIdx.x * 4 + wave) * 16;
    if (m0 >= N_DST2) return;
    int mrow = m0 + (lane & 15);
    int koff = (lane >> 4) * 8;

    f32x4 acc[3];
#pragma unroll
    for (int nb = 0; nb < 3; ++nb) acc[nb] = (f32x4){0.f, 0.f, 0.f, 0.f};

#pragma unroll
    for (int kb = 0; kb < 16; ++kb) {
        const ushort* A = (kb < 8)
            ? (hb  + (size_t)mrow * H_F + kb * 32 + koff)
            : (hn2 + (size_t)mrow * H_F + (kb - 8) * 32 + koff);
        short8 a = *(const short8*)A;
#pragma unroll
        for (int nb = 0; nb < 3; ++nb) {
            short8 b = *(const short8*)(P2 + ((size_t)(kb * 3 + nb) * 64 + lane) * 8);
            acc[nb] = __builtin_amdgcn_mfma_f32_16x16x32_bf16(a, b, acc[nb], 0, 0, 0);
        }
    }
    int crow0 = m0 + (lane >> 4) * 4;
    int ccol  = lane & 15;
#pragma unroll
    for (int nb = 0; nb < 3; ++nb) {
        int col = nb * 16 + ccol;
        if (col < N_CLS) {
            float bias = b2[col];
#pragma unroll
            for (int r = 0; r < 4; ++r)
                out[(size_t)(crow0 + r) * N_CLS + col] = acc[nb][r] + bias;
        }
    }
}

extern "C" void kernel_launch(void* const* d_in, const int* in_sizes, int n_in,
                              void* d_out, int out_size, void* d_ws, size_t ws_size,
                              hipStream_t stream) {
    const float* x   = (const float*)d_in[0];
    const float* Ws1 = (const float*)d_in[1];
    const float* Wn1 = (const float*)d_in[2];
    const float* b1  = (const float*)d_in[3];
    const float* Ws2 = (const float*)d_in[4];
    const float* Wn2 = (const float*)d_in[5];
    const float* b2  = (const float*)d_in[6];
    const int* src1  = (const int*)d_in[7];
    const int* dst1  = (const int*)d_in[8];
    const int* src2  = (const int*)d_in[9];
    const int* dst2  = (const int*)d_in[10];
    float* out = (float*)d_out;

    char* ws = (char*)d_ws;
    int*    rp1 = (int*)(ws + RP1_OFF);
    int*    rp2 = (int*)(ws + RP2_OFF);
    ushort* bps = (ushort*)(ws + BPS_OFF);
    ushort* bpn = (ushort*)(ws + BPN_OFF);
    ushort* bp2 = (ushort*)(ws + BP2_OFF);
    ushort* xb  = (ushort*)(ws + XB_OFF);
    ushort* hn1 = (ushort*)(ws + HN1_OFF);
    ushort* hb  = (ushort*)(ws + HB_OFF);
    ushort* hn2 = (ushort*)(ws + HN2_OFF);

    cast_x<<<200000 * IN_F / 4 / 256, 256, 0, stream>>>(x, xb);
    packB<<<16, 256, 0, stream>>>(Ws1, bps);
    packB<<<16, 256, 0, stream>>>(Wn1, bpn);
    packB2<<<12, 256, 0, stream>>>(Ws2, Wn2, bp2);
    build_rowptr<<<(N_DST1 + 1 + 255) / 256, 256, 0, stream>>>(dst1, E1, N_DST1 + 1, rp1);
    build_rowptr<<<(N_DST2 + 1 + 255) / 256, 256, 0, stream>>>(dst2, E2, N_DST2 + 1, rp2);
    agg1b<<<N_DST1, 64, 0, stream>>>(xb, src1, rp1, hn1);
    gemm1_mfma<<<(N_DST1 / 16 + 3) / 4, 256, 0, stream>>>(xb, hn1, bps, bpn, b1, hb);
    agg2b<<<N_DST2, 64, 0, stream>>>(hb, src2, rp2, hn2);
    gemm2_mfma<<<(N_DST2 / 16 + 3) / 4, 256, 0, stream>>>(hb, hn2, bp2, b2, out);
}

// Round 4
// 311.570 us; speedup vs baseline: 1.6712x; 1.1325x over previous
//
#include <hip/hip_runtime.h>

constexpr int N_DST1 = 50000;
constexpr int N_DST2 = 10000;
constexpr int E1     = 2000000;
constexpr int E2     = 400000;
constexpr int IN_F   = 128;
constexpr int H_F    = 256;
constexpr int N_CLS  = 47;

// Workspace layout (bytes)
constexpr size_t RP1_OFF = 0;          // 50001 int
constexpr size_t RP2_OFF = 204800;     // 10001 int
constexpr size_t BPS_OFF = 245760;     // Ws1 packed bf16 frags: 64 KB
constexpr size_t BPN_OFF = 311296;     // Wn1 packed: 64 KB
constexpr size_t BP2_OFF = 376832;     // [Ws2;Wn2] packed: 48 KB
constexpr size_t X8_OFF  = 430080;     // x fp8: 200000*128 = 25.6 MB
constexpr size_t HN1_OFF = 26030080;   // hn1 bf16: 12.8 MB
constexpr size_t HB_OFF  = 38830080;   // h bf16: 25.6 MB
constexpr size_t H8_OFF  = 64430080;   // h fp8: 12.8 MB
constexpr size_t HN2_OFF = 77230080;   // hn2 bf16: 5.12 MB
// total ~82.4 MB

using f32x4  = __attribute__((ext_vector_type(4))) float;
using f32x2  = __attribute__((ext_vector_type(2))) float;
using short8 = __attribute__((ext_vector_type(8))) short;

__device__ __forceinline__ ushort f2bf(float f) {
    union { float f; unsigned u; } v; v.f = f;
    unsigned u = v.u;
    return (ushort)((u + 0x7fffu + ((u >> 16) & 1u)) >> 16);
}
__device__ __forceinline__ float bflo(unsigned p) {
    union { unsigned u; float f; } v; v.u = p << 16; return v.f;
}
__device__ __forceinline__ float bfhi(unsigned p) {
    union { unsigned u; float f; } v; v.u = p & 0xffff0000u; return v.f;
}

// ---- x fp32 -> fp8 e4m3 (8 elems/thread) ----
__global__ __launch_bounds__(256) void cast_x8(const float* __restrict__ x,
                                               unsigned char* __restrict__ x8) {
    int i = blockIdx.x * 256 + threadIdx.x;  // groups of 8 floats
    float4 v0 = ((const float4*)x)[2 * i];
    float4 v1 = ((const float4*)x)[2 * i + 1];
    int p0 = __builtin_amdgcn_cvt_pk_fp8_f32(v0.x, v0.y, 0, false);
    p0     = __builtin_amdgcn_cvt_pk_fp8_f32(v0.z, v0.w, p0, true);
    int p1 = __builtin_amdgcn_cvt_pk_fp8_f32(v1.x, v1.y, 0, false);
    p1     = __builtin_amdgcn_cvt_pk_fp8_f32(v1.z, v1.w, p1, true);
    uint2 o; o.x = (unsigned)p0; o.y = (unsigned)p1;
    ((uint2*)x8)[i] = o;
}

// ---- all weight packing in one dispatch ----
// blocks 0..15: Ws1->bps ; 16..31: Wn1->bpn ; 32..43: [Ws2;Wn2]->bp2
__global__ __launch_bounds__(256) void pack_all(
    const float* __restrict__ Ws1, const float* __restrict__ Wn1,
    const float* __restrict__ Ws2, const float* __restrict__ Wn2,
    ushort* __restrict__ bps, ushort* __restrict__ bpn,
    ushort* __restrict__ bp2) {
    int b = blockIdx.x;
    if (b < 32) {
        const float* W = (b < 16) ? Ws1 : Wn1;
        ushort* P      = (b < 16) ? bps : bpn;
        int idx = (b & 15) * 256 + threadIdx.x;  // 0..4095
        int lane = idx & 63, kb = (idx >> 6) & 3, nb = idx >> 8;
        int n  = nb * 16 + (lane & 15);
        int k0 = kb * 32 + ((lane >> 4) * 8);
        ushort tmp[8];
#pragma unroll
        for (int j = 0; j < 8; ++j) tmp[j] = f2bf(W[(k0 + j) * H_F + n]);
        ((uint4*)P)[idx] = *(uint4*)tmp;
    } else {
        int idx = (b - 32) * 256 + threadIdx.x;  // 0..3071
        int lane = idx & 63, rem = idx >> 6;
        int nb = rem % 3, kb = rem / 3;
        int col = nb * 16 + (lane & 15);
        int k0  = (kb & 7) * 32 + ((lane >> 4) * 8);
        const float* W = (kb < 8) ? Ws2 : Wn2;
        ushort tmp[8];
#pragma unroll
        for (int j = 0; j < 8; ++j)
            tmp[j] = (col < N_CLS) ? f2bf(W[(k0 + j) * N_CLS + col]) : (ushort)0;
        ((uint4*)bp2)[(kb * 3 + nb) * 64 + lane] = *(uint4*)tmp;
    }
}

// ---- both rowptrs in one dispatch (dst sorted) ----
__global__ void rowptr_all(const int* __restrict__ dst1,
                           const int* __restrict__ dst2,
                           int* __restrict__ rp1, int* __restrict__ rp2) {
    int idx = blockIdx.x * blockDim.x + threadIdx.x;
    const int* dst; int* rp; int E; int target;
    if (idx <= N_DST1) { dst = dst1; rp = rp1; E = E1; target = idx; }
    else if (idx <= N_DST1 + 1 + N_DST2) {
        dst = dst2; rp = rp2; E = E2; target = idx - (N_DST1 + 1);
    } else return;
    int lo = 0, hi = E;
    while (lo < hi) {
        int mid = (lo + hi) >> 1;
        if (dst[mid] < target) lo = mid + 1; else hi = mid;
    }
    rp[target] = lo;
}

// ---- layer-1 mean agg over fp8 x: one wave/dst, 2 fp8/lane/edge ----
__global__ __launch_bounds__(64) void agg1b(const unsigned char* __restrict__ x8,
                                            const int* __restrict__ src,
                                            const int* __restrict__ rp,
                                            ushort* __restrict__ hn) {
    int d = blockIdx.x, t = threadIdx.x;
    int s = rp[d], e = rp[d + 1];
    const ushort* xr = (const ushort*)x8;  // row stride 64 ushorts (128 B)
    float a0 = 0.f, a1 = 0.f;
    for (int base = s; base < e; base += 64) {
        int rem = e - base;
        int n = rem < 64 ? rem : 64;
        int idx = src[base + (t < rem ? t : 0)];
        int j = 0;
        for (; j + 8 <= n; j += 8) {
            ushort u[8];
#pragma unroll
            for (int q = 0; q < 8; ++q) {
                int sq = __shfl(idx, j + q);
                u[q] = xr[sq * 64 + t];
            }
#pragma unroll
            for (int q = 0; q < 8; ++q) {
                f32x2 f = __builtin_amdgcn_cvt_pk_f32_fp8((int)u[q], false);
                a0 += f[0]; a1 += f[1];
            }
        }
        for (; j < n; ++j) {
            int sq = __shfl(idx, j);
            f32x2 f = __builtin_amdgcn_cvt_pk_f32_fp8((int)xr[sq * 64 + t], false);
            a0 += f[0]; a1 += f[1];
        }
    }
    float inv = 1.f / fmaxf((float)(e - s), 1.f);
    ((unsigned*)hn)[d * 64 + t] =
        (unsigned)f2bf(a0 * inv) | ((unsigned)f2bf(a1 * inv) << 16);
}

// ---- layer-2 mean agg over fp8 h: one wave/dst, 4 fp8/lane/edge ----
__global__ __launch_bounds__(64) void agg2b(const unsigned char* __restrict__ h8,
                                            const int* __restrict__ src,
                                            const int* __restrict__ rp,
                                            ushort* __restrict__ hn) {
    int d = blockIdx.x, t = threadIdx.x;
    int s = rp[d], e = rp[d + 1];
    const unsigned* hr = (const unsigned*)h8;  // row stride 64 uints (256 B)
    float a0 = 0.f, a1 = 0.f, a2 = 0.f, a3 = 0.f;
    for (int base = s; base < e; base += 64) {
        int rem = e - base;
        int n = rem < 64 ? rem : 64;
        int idx = src[base + (t < rem ? t : 0)];
        int j = 0;
        for (; j + 4 <= n; j += 4) {
            unsigned u[4];
#pragma unroll
            for (int q = 0; q < 4; ++q) {
                int sq = __shfl(idx, j + q);
                u[q] = hr[sq * 64 + t];
            }
#pragma unroll
            for (int q = 0; q < 4; ++q) {
                f32x2 f0 = __builtin_amdgcn_cvt_pk_f32_fp8((int)u[q], false);
                f32x2 f1 = __builtin_amdgcn_cvt_pk_f32_fp8((int)u[q], true);
                a0 += f0[0]; a1 += f0[1]; a2 += f1[0]; a3 += f1[1];
            }
        }
        for (; j < n; ++j) {
            int sq = __shfl(idx, j);
            unsigned u = hr[sq * 64 + t];
            f32x2 f0 = __builtin_amdgcn_cvt_pk_f32_fp8((int)u, false);
            f32x2 f1 = __builtin_amdgcn_cvt_pk_f32_fp8((int)u, true);
            a0 += f0[0]; a1 += f0[1]; a2 += f1[0]; a3 += f1[1];
        }
    }
    float inv = 1.f / fmaxf((float)(e - s), 1.f);
    uint2 o;
    o.x = (unsigned)f2bf(a0 * inv) | ((unsigned)f2bf(a1 * inv) << 16);
    o.y = (unsigned)f2bf(a2 * inv) | ((unsigned)f2bf(a3 * inv) << 16);
    ((uint2*)hn)[d * 64 + t] = o;
}

// ---- layer 1 GEMM (MFMA; self-A from fp32 x, neigh-A from bf16 hn1) ----
__global__ __launch_bounds__(256) void gemm1_mfma(
    const float* __restrict__ x, const ushort* __restrict__ hn1,
    const ushort* __restrict__ BpS, const ushort* __restrict__ BpN,
    const float* __restrict__ b1, ushort* __restrict__ hb,
    unsigned char* __restrict__ h8) {
    __shared__ ushort bsm[16 * 64 * 8];  // 16 KB stage
    int tid = threadIdx.x;
    int wave = tid >> 6, lane = tid & 63;
    int m0 = (blockIdx.x * 4 + wave) * 16;
    int mrow = m0 + (lane & 15);
    bool active = (m0 < N_DST1);
    if (mrow >= N_DST1) mrow = 0;
    int koff = (lane >> 4) * 8;

    f32x4 acc[16];
#pragma unroll
    for (int nb = 0; nb < 16; ++nb) acc[nb] = (f32x4){0.f, 0.f, 0.f, 0.f};

    for (int ph = 0; ph < 2; ++ph) {
        const uint4* Pg = (const uint4*)((ph == 0) ? BpS : BpN);
        const float*  Af = x   + (size_t)mrow * IN_F;   // ph 0
        const ushort* Ah = hn1 + (size_t)mrow * IN_F;   // ph 1
        for (int kb = 0; kb < 4; ++kb) {
            __syncthreads();
#pragma unroll
            for (int i = 0; i < 4; ++i) {
                int u = tid + 256 * i;
                int nb = u >> 6, l6 = u & 63;
                ((uint4*)bsm)[u] = Pg[(nb * 4 + kb) * 64 + l6];
            }
            __syncthreads();
            short8 a;
            if (ph == 0) {
                float4 a0 = *(const float4*)(Af + kb * 32 + koff);
                float4 a1 = *(const float4*)(Af + kb * 32 + koff + 4);
                a[0] = (short)f2bf(a0.x); a[1] = (short)f2bf(a0.y);
                a[2] = (short)f2bf(a0.z); a[3] = (short)f2bf(a0.w);
                a[4] = (short)f2bf(a1.x); a[5] = (short)f2bf(a1.y);
                a[6] = (short)f2bf(a1.z); a[7] = (short)f2bf(a1.w);
            } else {
                a = *(const short8*)(Ah + kb * 32 + koff);
            }
#pragma unroll
            for (int nb = 0; nb < 16; ++nb) {
                short8 b = *(const short8*)&bsm[(nb * 64 + lane) * 8];
                acc[nb] = __builtin_amdgcn_mfma_f32_16x16x32_bf16(a, b, acc[nb], 0, 0, 0);
            }
        }
    }
    if (!active) return;
    int crow0 = m0 + (lane >> 4) * 4;
    int ccol  = lane & 15;
#pragma unroll
    for (int nb = 0; nb < 16; ++nb) {
        float bias = b1[nb * 16 + ccol];
#pragma unroll
        for (int r = 0; r < 4; ++r) {
            int row = crow0 + r;
            if (row < N_DST1) {
                float v = fmaxf(acc[nb][r] + bias, 0.f);
                size_t col = (size_t)nb * 16 + ccol;
                hb[(size_t)row * H_F + col] = f2bf(v);
                int p = __builtin_amdgcn_cvt_pk_fp8_f32(v, v, 0, false);
                h8[(size_t)row * H_F + col] = (unsigned char)(p & 0xff);
            }
        }
    }
}

// ---- layer 2 GEMM (MFMA, K=512 over [hb|hn2], N padded to 48) ----
__global__ __launch_bounds__(256) void gemm2_mfma(
    const ushort* __restrict__ hb, const ushort* __restrict__ hn2,
    const ushort* __restrict__ P2, const float* __restrict__ b2,
    float* __restrict__ out) {
    int tid = threadIdx.x;
    int wave = tid >> 6, lane = tid & 63;
    int m0 = (blockIdx.x * 4 + wave) * 16;
    if (m0 >= N_DST2) return;
    int mrow = m0 + (lane & 15);
    int koff = (lane >> 4) * 8;

    f32x4 acc[3];
#pragma unroll
    for (int nb = 0; nb < 3; ++nb) acc[nb] = (f32x4){0.f, 0.f, 0.f, 0.f};

#pragma unroll
    for (int kb = 0; kb < 16; ++kb) {
        const ushort* A = (kb < 8)
            ? (hb  + (size_t)mrow * H_F + kb * 32 + koff)
            : (hn2 + (size_t)mrow * H_F + (kb - 8) * 32 + koff);
        short8 a = *(const short8*)A;
#pragma unroll
        for (int nb = 0; nb < 3; ++nb) {
            short8 b = *(const short8*)(P2 + ((size_t)(kb * 3 + nb) * 64 + lane) * 8);
            acc[nb] = __builtin_amdgcn_mfma_f32_16x16x32_bf16(a, b, acc[nb], 0, 0, 0);
        }
    }
    int crow0 = m0 + (lane >> 4) * 4;
    int ccol  = lane & 15;
#pragma unroll
    for (int nb = 0; nb < 3; ++nb) {
        int col = nb * 16 + ccol;
        if (col < N_CLS) {
            float bias = b2[col];
#pragma unroll
            for (int r = 0; r < 4; ++r)
                out[(size_t)(crow0 + r) * N_CLS + col] = acc[nb][r] + bias;
        }
    }
}

extern "C" void kernel_launch(void* const* d_in, const int* in_sizes, int n_in,
                              void* d_out, int out_size, void* d_ws, size_t ws_size,
                              hipStream_t stream) {
    const float* x   = (const float*)d_in[0];
    const float* Ws1 = (const float*)d_in[1];
    const float* Wn1 = (const float*)d_in[2];
    const float* b1  = (const float*)d_in[3];
    const float* Ws2 = (const float*)d_in[4];
    const float* Wn2 = (const float*)d_in[5];
    const float* b2  = (const float*)d_in[6];
    const int* src1  = (const int*)d_in[7];
    const int* dst1  = (const int*)d_in[8];
    const int* src2  = (const int*)d_in[9];
    const int* dst2  = (const int*)d_in[10];
    float* out = (float*)d_out;

    char* ws = (char*)d_ws;
    int*           rp1 = (int*)(ws + RP1_OFF);
    int*           rp2 = (int*)(ws + RP2_OFF);
    ushort*        bps = (ushort*)(ws + BPS_OFF);
    ushort*        bpn = (ushort*)(ws + BPN_OFF);
    ushort*        bp2 = (ushort*)(ws + BP2_OFF);
    unsigned char* x8  = (unsigned char*)(ws + X8_OFF);
    ushort*        hn1 = (ushort*)(ws + HN1_OFF);
    ushort*        hb  = (ushort*)(ws + HB_OFF);
    unsigned char* h8  = (unsigned char*)(ws + H8_OFF);
    ushort*        hn2 = (ushort*)(ws + HN2_OFF);

    cast_x8<<<200000 * IN_F / 8 / 256, 256, 0, stream>>>(x, x8);
    pack_all<<<44, 256, 0, stream>>>(Ws1, Wn1, Ws2, Wn2, bps, bpn, bp2);
    rowptr_all<<<(N_DST1 + N_DST2 + 2 + 255) / 256, 256, 0, stream>>>(dst1, dst2, rp1, rp2);
    agg1b<<<N_DST1, 64, 0, stream>>>(x8, src1, rp1, hn1);
    gemm1_mfma<<<(N_DST1 / 16 + 3) / 4, 256, 0, stream>>>(x, hn1, bps, bpn, b1, hb, h8);
    agg2b<<<N_DST2, 64, 0, stream>>>(h8, src2, rp2, hn2);
    gemm2_mfma<<<(N_DST2 / 16 + 3) / 4, 256, 0, stream>>>(hb, hn2, bp2, b2, out);
}

// Round 5
// 306.600 us; speedup vs baseline: 1.6983x; 1.0162x over previous
//
#include <hip/hip_runtime.h>

constexpr int N_DST1 = 50000;
constexpr int N_DST2 = 10000;
constexpr int E1     = 2000000;
constexpr int E2     = 400000;
constexpr int IN_F   = 128;
constexpr int H_F    = 256;
constexpr int N_CLS  = 47;

// Workspace layout (bytes)
constexpr size_t RP1_OFF = 0;          // 50001 int
constexpr size_t RP2_OFF = 204800;     // 10001 int
constexpr size_t BPS_OFF = 245760;     // Ws1 packed bf16 frags: 64 KB
constexpr size_t BPN_OFF = 311296;     // Wn1 packed: 64 KB
constexpr size_t BP2_OFF = 376832;     // [Ws2;Wn2] packed: 48 KB
constexpr size_t X8_OFF  = 430080;     // x fp8: 200000*128 = 25.6 MB
constexpr size_t HN1_OFF = 26030080;   // hn1 bf16: 12.8 MB
constexpr size_t HB_OFF  = 38830080;   // h bf16: 25.6 MB
constexpr size_t H8_OFF  = 64430080;   // h fp8: 12.8 MB
constexpr size_t HN2_OFF = 77230080;   // hn2 bf16: 5.12 MB
// total ~82.4 MB

using f32x4  = __attribute__((ext_vector_type(4))) float;
using f32x2  = __attribute__((ext_vector_type(2))) float;
using short8 = __attribute__((ext_vector_type(8))) short;

__device__ __forceinline__ ushort f2bf(float f) {
    union { float f; unsigned u; } v; v.f = f;
    unsigned u = v.u;
    return (ushort)((u + 0x7fffu + ((u >> 16) & 1u)) >> 16);
}

// ---- fused setup: cast x->fp8 | pack weights | rowptrs ----
constexpr int CAST_BLKS = 200000 * IN_F / 8 / 256;  // 12500
constexpr int PACK_BLKS = 44;
constexpr int RP_BLKS   = (N_DST1 + N_DST2 + 2 + 255) / 256;  // 235

__global__ __launch_bounds__(256) void setup_all(
    const float* __restrict__ x, unsigned char* __restrict__ x8,
    const float* __restrict__ Ws1, const float* __restrict__ Wn1,
    const float* __restrict__ Ws2, const float* __restrict__ Wn2,
    ushort* __restrict__ bps, ushort* __restrict__ bpn, ushort* __restrict__ bp2,
    const int* __restrict__ dst1, const int* __restrict__ dst2,
    int* __restrict__ rp1, int* __restrict__ rp2) {
    int b = blockIdx.x;
    if (b < CAST_BLKS) {
        int i = b * 256 + threadIdx.x;  // groups of 8 floats
        float4 v0 = ((const float4*)x)[2 * i];
        float4 v1 = ((const float4*)x)[2 * i + 1];
        int p0 = __builtin_amdgcn_cvt_pk_fp8_f32(v0.x, v0.y, 0, false);
        p0     = __builtin_amdgcn_cvt_pk_fp8_f32(v0.z, v0.w, p0, true);
        int p1 = __builtin_amdgcn_cvt_pk_fp8_f32(v1.x, v1.y, 0, false);
        p1     = __builtin_amdgcn_cvt_pk_fp8_f32(v1.z, v1.w, p1, true);
        uint2 o; o.x = (unsigned)p0; o.y = (unsigned)p1;
        ((uint2*)x8)[i] = o;
    } else if (b < CAST_BLKS + PACK_BLKS) {
        int pb = b - CAST_BLKS;
        if (pb < 32) {
            const float* W = (pb < 16) ? Ws1 : Wn1;
            ushort* P      = (pb < 16) ? bps : bpn;
            int idx = (pb & 15) * 256 + threadIdx.x;  // 0..4095
            int lane = idx & 63, kb = (idx >> 6) & 3, nb = idx >> 8;
            int n  = nb * 16 + (lane & 15);
            int k0 = kb * 32 + ((lane >> 4) * 8);
            ushort tmp[8];
#pragma unroll
            for (int j = 0; j < 8; ++j) tmp[j] = f2bf(W[(k0 + j) * H_F + n]);
            ((uint4*)P)[idx] = *(uint4*)tmp;
        } else {
            int idx = (pb - 32) * 256 + threadIdx.x;  // 0..3071
            if (idx < 3072) {
                int lane = idx & 63, rem = idx >> 6;
                int nb = rem % 3, kb = rem / 3;
                int col = nb * 16 + (lane & 15);
                int k0  = (kb & 7) * 32 + ((lane >> 4) * 8);
                const float* W = (kb < 8) ? Ws2 : Wn2;
                ushort tmp[8];
#pragma unroll
                for (int j = 0; j < 8; ++j)
                    tmp[j] = (col < N_CLS) ? f2bf(W[(k0 + j) * N_CLS + col]) : (ushort)0;
                ((uint4*)bp2)[(kb * 3 + nb) * 64 + lane] = *(uint4*)tmp;
            }
        }
    } else {
        int idx = (b - CAST_BLKS - PACK_BLKS) * 256 + threadIdx.x;
        const int* dst; int* rp; int E; int target;
        if (idx <= N_DST1) { dst = dst1; rp = rp1; E = E1; target = idx; }
        else if (idx <= N_DST1 + 1 + N_DST2) {
            dst = dst2; rp = rp2; E = E2; target = idx - (N_DST1 + 1);
        } else return;
        int lo = 0, hi = E;
        while (lo < hi) {
            int mid = (lo + hi) >> 1;
            if (dst[mid] < target) lo = mid + 1; else hi = mid;
        }
        rp[target] = lo;
    }
}

// ---- layer-1 mean agg: one wave/dst; 2 edges per load (half-wave split) ----
// x8 row = 128 B = 32 uints; lane t in half h=(t>>5) covers feats 4*(t&31)..+3
// of edge parity h. Scalar (wave-uniform) index loads.
__global__ __launch_bounds__(64) void agg1b(const unsigned char* __restrict__ x8,
                                            const int* __restrict__ src,
                                            const int* __restrict__ rp,
                                            ushort* __restrict__ hn) {
    int d = blockIdx.x, t = threadIdx.x;
    int s = rp[d], e = rp[d + 1];
    const unsigned* x1 = (const unsigned*)x8;  // row stride 32 uints
    int half = t >> 5, li = t & 31;
    float a0 = 0.f, a1 = 0.f, a2 = 0.f, a3 = 0.f;
    int deg = e - s;
    int npairs = deg >> 1;
    int j = 0;
    for (; j + 4 <= npairs; j += 4) {
        int b0 = s + 2 * j;
        int i0 = src[b0],     i1 = src[b0 + 1], i2 = src[b0 + 2], i3 = src[b0 + 3];
        int i4 = src[b0 + 4], i5 = src[b0 + 5], i6 = src[b0 + 6], i7 = src[b0 + 7];
        unsigned v0 = x1[(half ? i1 : i0) * 32 + li];
        unsigned v1 = x1[(half ? i3 : i2) * 32 + li];
        unsigned v2 = x1[(half ? i5 : i4) * 32 + li];
        unsigned v3 = x1[(half ? i7 : i6) * 32 + li];
#pragma unroll
        for (int q = 0; q < 4; ++q) {
            unsigned v = (q == 0) ? v0 : (q == 1) ? v1 : (q == 2) ? v2 : v3;
            f32x2 f0 = __builtin_amdgcn_cvt_pk_f32_fp8((int)v, false);
            f32x2 f1 = __builtin_amdgcn_cvt_pk_f32_fp8((int)v, true);
            a0 += f0[0]; a1 += f0[1]; a2 += f1[0]; a3 += f1[1];
        }
    }
    for (; j < npairs; ++j) {
        int b0 = s + 2 * j;
        int i0 = src[b0], i1 = src[b0 + 1];
        unsigned v = x1[(half ? i1 : i0) * 32 + li];
        f32x2 f0 = __builtin_amdgcn_cvt_pk_f32_fp8((int)v, false);
        f32x2 f1 = __builtin_amdgcn_cvt_pk_f32_fp8((int)v, true);
        a0 += f0[0]; a1 += f0[1]; a2 += f1[0]; a3 += f1[1];
    }
    if (deg & 1) {
        int it = src[e - 1];
        if (half == 0) {
            unsigned v = x1[it * 32 + li];
            f32x2 f0 = __builtin_amdgcn_cvt_pk_f32_fp8((int)v, false);
            f32x2 f1 = __builtin_amdgcn_cvt_pk_f32_fp8((int)v, true);
            a0 += f0[0]; a1 += f0[1]; a2 += f1[0]; a3 += f1[1];
        }
    }
    // combine parity halves (valid for lanes 0..31)
    float c0 = a0 + __shfl(a0, li + 32);
    float c1 = a1 + __shfl(a1, li + 32);
    float c2 = a2 + __shfl(a2, li + 32);
    float c3 = a3 + __shfl(a3, li + 32);
    if (t < 32) {
        float inv = 1.f / fmaxf((float)deg, 1.f);
        uint2 o;
        o.x = (unsigned)f2bf(c0 * inv) | ((unsigned)f2bf(c1 * inv) << 16);
        o.y = (unsigned)f2bf(c2 * inv) | ((unsigned)f2bf(c3 * inv) << 16);
        ((uint2*)hn)[d * 32 + li] = o;
    }
}

// ---- layer-2 mean agg: one wave/dst; 2 edges per uint2 load ----
// h8 row = 256 B = 32 uint2; lane covers feats 8*(t&31)..+7 of parity (t>>5)
__global__ __launch_bounds__(64) void agg2b(const unsigned char* __restrict__ h8,
                                            const int* __restrict__ src,
                                            const int* __restrict__ rp,
                                            ushort* __restrict__ hn) {
    int d = blockIdx.x, t = threadIdx.x;
    int s = rp[d], e = rp[d + 1];
    const uint2* h2 = (const uint2*)h8;  // row stride 32 uint2
    int half = t >> 5, li = t & 31;
    float a[8] = {};
    int deg = e - s;
    int npairs = deg >> 1;
    int j = 0;
    for (; j + 2 <= npairs; j += 2) {
        int b0 = s + 2 * j;
        int i0 = src[b0], i1 = src[b0 + 1], i2 = src[b0 + 2], i3 = src[b0 + 3];
        uint2 v0 = h2[(half ? i1 : i0) * 32 + li];
        uint2 v1 = h2[(half ? i3 : i2) * 32 + li];
#pragma unroll
        for (int q = 0; q < 2; ++q) {
            uint2 v = q ? v1 : v0;
            f32x2 f0 = __builtin_amdgcn_cvt_pk_f32_fp8((int)v.x, false);
            f32x2 f1 = __builtin_amdgcn_cvt_pk_f32_fp8((int)v.x, true);
            f32x2 f2 = __builtin_amdgcn_cvt_pk_f32_fp8((int)v.y, false);
            f32x2 f3 = __builtin_amdgcn_cvt_pk_f32_fp8((int)v.y, true);
            a[0] += f0[0]; a[1] += f0[1]; a[2] += f1[0]; a[3] += f1[1];
            a[4] += f2[0]; a[5] += f2[1]; a[6] += f3[0]; a[7] += f3[1];
        }
    }
    for (; j < npairs; ++j) {
        int b0 = s + 2 * j;
        int i0 = src[b0], i1 = src[b0 + 1];
        uint2 v = h2[(half ? i1 : i0) * 32 + li];
        f32x2 f0 = __builtin_amdgcn_cvt_pk_f32_fp8((int)v.x, false);
        f32x2 f1 = __builtin_amdgcn_cvt_pk_f32_fp8((int)v.x, true);
        f32x2 f2 = __builtin_amdgcn_cvt_pk_f32_fp8((int)v.y, false);
        f32x2 f3 = __builtin_amdgcn_cvt_pk_f32_fp8((int)v.y, true);
        a[0] += f0[0]; a[1] += f0[1]; a[2] += f1[0]; a[3] += f1[1];
        a[4] += f2[0]; a[5] += f2[1]; a[6] += f3[0]; a[7] += f3[1];
    }
    if (deg & 1) {
        int it = src[e - 1];
        if (half == 0) {
            uint2 v = h2[it * 32 + li];
            f32x2 f0 = __builtin_amdgcn_cvt_pk_f32_fp8((int)v.x, false);
            f32x2 f1 = __builtin_amdgcn_cvt_pk_f32_fp8((int)v.x, true);
            f32x2 f2 = __builtin_amdgcn_cvt_pk_f32_fp8((int)v.y, false);
            f32x2 f3 = __builtin_amdgcn_cvt_pk_f32_fp8((int)v.y, true);
            a[0] += f0[0]; a[1] += f0[1]; a[2] += f1[0]; a[3] += f1[1];
            a[4] += f2[0]; a[5] += f2[1]; a[6] += f3[0]; a[7] += f3[1];
        }
    }
    float c[8];
#pragma unroll
    for (int q = 0; q < 8; ++q) c[q] = a[q] + __shfl(a[q], li + 32);
    if (t < 32) {
        float inv = 1.f / fmaxf((float)deg, 1.f);
        uint4 o;
        o.x = (unsigned)f2bf(c[0] * inv) | ((unsigned)f2bf(c[1] * inv) << 16);
        o.y = (unsigned)f2bf(c[2] * inv) | ((unsigned)f2bf(c[3] * inv) << 16);
        o.z = (unsigned)f2bf(c[4] * inv) | ((unsigned)f2bf(c[5] * inv) << 16);
        o.w = (unsigned)f2bf(c[6] * inv) | ((unsigned)f2bf(c[7] * inv) << 16);
        ((uint4*)hn)[d * 32 + li] = o;
    }
}

// ---- layer 1 GEMM (MFMA; self-A from fp32 x, neigh-A from bf16 hn1) ----
__global__ __launch_bounds__(256) void gemm1_mfma(
    const float* __restrict__ x, const ushort* __restrict__ hn1,
    const ushort* __restrict__ BpS, const ushort* __restrict__ BpN,
    const float* __restrict__ b1, ushort* __restrict__ hb,
    unsigned char* __restrict__ h8) {
    __shared__ ushort bsm[16 * 64 * 8];  // 16 KB stage
    int tid = threadIdx.x;
    int wave = tid >> 6, lane = tid & 63;
    int m0 = (blockIdx.x * 4 + wave) * 16;
    int mrow = m0 + (lane & 15);
    bool active = (m0 < N_DST1);
    if (mrow >= N_DST1) mrow = 0;
    int koff = (lane >> 4) * 8;

    f32x4 acc[16];
#pragma unroll
    for (int nb = 0; nb < 16; ++nb) acc[nb] = (f32x4){0.f, 0.f, 0.f, 0.f};

    for (int ph = 0; ph < 2; ++ph) {
        const uint4* Pg = (const uint4*)((ph == 0) ? BpS : BpN);
        const float*  Af = x   + (size_t)mrow * IN_F;
        const ushort* Ah = hn1 + (size_t)mrow * IN_F;
        for (int kb = 0; kb < 4; ++kb) {
            __syncthreads();
#pragma unroll
            for (int i = 0; i < 4; ++i) {
                int u = tid + 256 * i;
                int nb = u >> 6, l6 = u & 63;
                ((uint4*)bsm)[u] = Pg[(nb * 4 + kb) * 64 + l6];
            }
            __syncthreads();
            short8 a;
            if (ph == 0) {
                float4 a0 = *(const float4*)(Af + kb * 32 + koff);
                float4 a1 = *(const float4*)(Af + kb * 32 + koff + 4);
                a[0] = (short)f2bf(a0.x); a[1] = (short)f2bf(a0.y);
                a[2] = (short)f2bf(a0.z); a[3] = (short)f2bf(a0.w);
                a[4] = (short)f2bf(a1.x); a[5] = (short)f2bf(a1.y);
                a[6] = (short)f2bf(a1.z); a[7] = (short)f2bf(a1.w);
            } else {
                a = *(const short8*)(Ah + kb * 32 + koff);
            }
#pragma unroll
            for (int nb = 0; nb < 16; ++nb) {
                short8 b = *(const short8*)&bsm[(nb * 64 + lane) * 8];
                acc[nb] = __builtin_amdgcn_mfma_f32_16x16x32_bf16(a, b, acc[nb], 0, 0, 0);
            }
        }
    }
    if (!active) return;
    int crow0 = m0 + (lane >> 4) * 4;
    int ccol  = lane & 15;
#pragma unroll
    for (int nb = 0; nb < 16; ++nb) {
        float bias = b1[nb * 16 + ccol];
#pragma unroll
        for (int r = 0; r < 4; ++r) {
            int row = crow0 + r;
            if (row < N_DST1) {
                float v = fmaxf(acc[nb][r] + bias, 0.f);
                size_t col = (size_t)nb * 16 + ccol;
                hb[(size_t)row * H_F + col] = f2bf(v);
                int p = __builtin_amdgcn_cvt_pk_fp8_f32(v, v, 0, false);
                h8[(size_t)row * H_F + col] = (unsigned char)(p & 0xff);
            }
        }
    }
}

// ---- layer 2 GEMM (MFMA, K=512 over [hb|hn2], N padded to 48) ----
__global__ __launch_bounds__(256) void gemm2_mfma(
    const ushort* __restrict__ hb, const ushort* __restrict__ hn2,
    const ushort* __restrict__ P2, const float* __restrict__ b2,
    float* __restrict__ out) {
    int tid = threadIdx.x;
    int wave = tid >> 6, lane = tid & 63;
    int m0 = (blockIdx.x * 4 + wave) * 16;
    if (m0 >= N_DST2) return;
    int mrow = m0 + (lane & 15);
    int koff = (lane >> 4) * 8;

    f32x4 acc[3];
#pragma unroll
    for (int nb = 0; nb < 3; ++nb) acc[nb] = (f32x4){0.f, 0.f, 0.f, 0.f};

#pragma unroll
    for (int kb = 0; kb < 16; ++kb) {
        const ushort* A = (kb < 8)
            ? (hb  + (size_t)mrow * H_F + kb * 32 + koff)
            : (hn2 + (size_t)mrow * H_F + (kb - 8) * 32 + koff);
        short8 a = *(const short8*)A;
#pragma unroll
        for (int nb = 0; nb < 3; ++nb) {
            short8 b = *(const short8*)(P2 + ((size_t)(kb * 3 + nb) * 64 + lane) * 8);
            acc[nb] = __builtin_amdgcn_mfma_f32_16x16x32_bf16(a, b, acc[nb], 0, 0, 0);
        }
    }
    int crow0 = m0 + (lane >> 4) * 4;
    int ccol  = lane & 15;
#pragma unroll
    for (int nb = 0; nb < 3; ++nb) {
        int col = nb * 16 + ccol;
        if (col < N_CLS) {
            float bias = b2[col];
#pragma unroll
            for (int r = 0; r < 4; ++r)
                out[(size_t)(crow0 + r) * N_CLS + col] = acc[nb][r] + bias;
        }
    }
}

extern "C" void kernel_launch(void* const* d_in, const int* in_sizes, int n_in,
                              void* d_out, int out_size, void* d_ws, size_t ws_size,
                              hipStream_t stream) {
    const float* x   = (const float*)d_in[0];
    const float* Ws1 = (const float*)d_in[1];
    const float* Wn1 = (const float*)d_in[2];
    const float* b1  = (const float*)d_in[3];
    const float* Ws2 = (const float*)d_in[4];
    const float* Wn2 = (const float*)d_in[5];
    const float* b2  = (const float*)d_in[6];
    const int* src1  = (const int*)d_in[7];
    const int* dst1  = (const int*)d_in[8];
    const int* src2  = (const int*)d_in[9];
    const int* dst2  = (const int*)d_in[10];
    float* out = (float*)d_out;

    char* ws = (char*)d_ws;
    int*           rp1 = (int*)(ws + RP1_OFF);
    int*           rp2 = (int*)(ws + RP2_OFF);
    ushort*        bps = (ushort*)(ws + BPS_OFF);
    ushort*        bpn = (ushort*)(ws + BPN_OFF);
    ushort*        bp2 = (ushort*)(ws + BP2_OFF);
    unsigned char* x8  = (unsigned char*)(ws + X8_OFF);
    ushort*        hn1 = (ushort*)(ws + HN1_OFF);
    ushort*        hb  = (ushort*)(ws + HB_OFF);
    unsigned char* h8  = (unsigned char*)(ws + H8_OFF);
    ushort*        hn2 = (ushort*)(ws + HN2_OFF);

    setup_all<<<CAST_BLKS + PACK_BLKS + RP_BLKS, 256, 0, stream>>>(
        x, x8, Ws1, Wn1, Ws2, Wn2, bps, bpn, bp2, dst1, dst2, rp1, rp2);
    agg1b<<<N_DST1, 64, 0, stream>>>(x8, src1, rp1, hn1);
    gemm1_mfma<<<(N_DST1 / 16 + 3) / 4, 256, 0, stream>>>(x, hn1, bps, bpn, b1, hb, h8);
    agg2b<<<N_DST2, 64, 0, stream>>>(h8, src2, rp2, hn2);
    gemm2_mfma<<<(N_DST2 / 16 + 3) / 4, 256, 0, stream>>>(hb, hn2, bp2, b2, out);
}